// Round 3
// baseline (841.193 us; speedup 1.0000x reference)
//
#include <hip/hip_runtime.h>

// Problem constants: N=256, S=512, D=512, C=512, R=64, P=64, CLASSES=1000
// Outputs: logits [256,1000] @0, recon [256,512] @256000, eff_weights [256,512] @387072

typedef unsigned short u16;
using bf16x8 = __attribute__((ext_vector_type(8))) short;
using f32x4  = __attribute__((ext_vector_type(4))) float;

#define INV_SCALE 0.04419417382415922f  // 1/sqrt(512)

__device__ __forceinline__ u16 f2bf(float f) {
  union { float f; unsigned int u; } v; v.f = f;
  unsigned int r = v.u + 0x7FFFu + ((v.u >> 16) & 1u);  // RNE
  return (u16)(r >> 16);
}
__device__ __forceinline__ float bf2f(u16 u) {
  union { unsigned int u; float f; } v; v.u = ((unsigned int)u) << 16;
  return v.f;
}
__device__ __forceinline__ float red16_max(float v) {
#pragma unroll
  for (int m = 1; m < 16; m <<= 1) v = fmaxf(v, __shfl_xor(v, m));
  return v;
}
__device__ __forceinline__ float red16_sum(float v) {
#pragma unroll
  for (int m = 1; m < 16; m <<= 1) v += __shfl_xor(v, m);
  return v;
}

// ---------------- prep1: CBext[576][512] bf16 = [codebook ; prot_codebook zero-padded] ----
__global__ __launch_bounds__(256) void k_prep1(const float* __restrict__ CB,
                                               const float* __restrict__ PC,
                                               u16* __restrict__ CBext) {
  int idx = blockIdx.x * 256 + threadIdx.x;  // 576*512 = 294912
  int row = idx >> 9, col = idx & 511;
  float v;
  if (row < 512) v = CB[idx];
  else { int r = row - 512; v = (col < 64) ? PC[r * 64 + col] : 0.f; }
  CBext[idx] = f2bf(v);
}

// ---------------- prep2: M1T[r][c] = sum_p CB[c][p]*PC[r][p], bf16 [64][512] -------------
__global__ __launch_bounds__(256) void k_prep2(const float* __restrict__ CB,
                                               const float* __restrict__ PC,
                                               u16* __restrict__ M1T) {
  __shared__ float pc[64];
  int r = blockIdx.x, tid = threadIdx.x;
  if (tid < 64) pc[tid] = PC[r * 64 + tid];
  __syncthreads();
  for (int c = tid; c < 512; c += 256) {
    const float* cb = CB + (size_t)c * 512;
    float s = 0.f;
#pragma unroll 8
    for (int p = 0; p < 64; ++p) s += cb[p] * pc[p];
    M1T[r * 512 + c] = f2bf(s);
  }
}

// ---------------- prep3: per-n query pipeline: code_w, prot_code_w ------------------------
__global__ __launch_bounds__(256) void k_prep3(const float* __restrict__ q,
                                               const float* __restrict__ Wq,
                                               const u16* __restrict__ CBext,
                                               const float* __restrict__ PC,
                                               float* __restrict__ cw_g,
                                               float* __restrict__ pcw_g) {
  __shared__ float qs[512], qps[512], cws[512], red[8], pqr[64];
  int n = blockIdx.x, tid = threadIdx.x;
  int wv = tid >> 6, ln = tid & 63;
  for (int i = tid; i < 512; i += 256) qs[i] = q[(size_t)n * 512 + i];
  __syncthreads();
  // q_proj = q @ Wq^T
#pragma unroll
  for (int h = 0; h < 2; ++h) {
    int i = tid + h * 256;
    const float* wr = Wq + (size_t)i * 512;
    float s = 0.f;
    for (int d = 0; d < 512; d += 4) {
      float4 w4 = *(const float4*)(wr + d);
      s += qs[d] * w4.x + qs[d + 1] * w4.y + qs[d + 2] * w4.z + qs[d + 3] * w4.w;
    }
    qps[i] = s;
  }
  __syncthreads();
  // code logits (vs bf16 codebook) + softmax over 512
  float cl[2];
#pragma unroll
  for (int h = 0; h < 2; ++h) {
    int c = tid + h * 256;
    const u16* cr = CBext + (size_t)c * 512;
    float s = 0.f;
    for (int d = 0; d < 512; d += 8) {
      uint4 u = *(const uint4*)(cr + d);
      s += bf2f((u16)(u.x & 0xffff)) * qps[d + 0];
      s += bf2f((u16)(u.x >> 16))    * qps[d + 1];
      s += bf2f((u16)(u.y & 0xffff)) * qps[d + 2];
      s += bf2f((u16)(u.y >> 16))    * qps[d + 3];
      s += bf2f((u16)(u.z & 0xffff)) * qps[d + 4];
      s += bf2f((u16)(u.z >> 16))    * qps[d + 5];
      s += bf2f((u16)(u.w & 0xffff)) * qps[d + 6];
      s += bf2f((u16)(u.w >> 16))    * qps[d + 7];
    }
    cl[h] = s * INV_SCALE;
  }
  float m = fmaxf(cl[0], cl[1]);
#pragma unroll
  for (int mk = 1; mk < 64; mk <<= 1) m = fmaxf(m, __shfl_xor(m, mk));
  if (ln == 0) red[wv] = m;
  __syncthreads();
  m = fmaxf(fmaxf(red[0], red[1]), fmaxf(red[2], red[3]));
  float e0 = __expf(cl[0] - m), e1 = __expf(cl[1] - m);
  float ssum = e0 + e1;
#pragma unroll
  for (int mk = 1; mk < 64; mk <<= 1) ssum += __shfl_xor(ssum, mk);
  if (ln == 0) red[4 + wv] = ssum;
  __syncthreads();
  float inv = 1.f / (red[4] + red[5] + red[6] + red[7]);
  float w0 = e0 * inv, w1 = e1 * inv;
  cws[tid] = w0; cws[tid + 256] = w1;
  cw_g[(size_t)n * 512 + tid] = w0;
  cw_g[(size_t)n * 512 + tid + 256] = w1;
  __syncthreads();
  // query_base (first 64 channels) and protected residual
  if (tid < 64) {
    float qb = 0.f;
    for (int c = 0; c < 512; ++c) qb += cws[c] * bf2f(CBext[(size_t)c * 512 + tid]);
    pqr[tid] = qps[tid] - qb;
  }
  __syncthreads();
  if (tid < 64) {  // wave 0: prot softmax over 64
    const float* pr = PC + tid * 64;
    float s = 0.f;
#pragma unroll 8
    for (int p = 0; p < 64; ++p) s += pqr[p] * pr[p];
    s *= INV_SCALE;
    float mm = s;
#pragma unroll
    for (int mk = 1; mk < 64; mk <<= 1) mm = fmaxf(mm, __shfl_xor(mm, mk));
    float e = __expf(s - mm);
    float t = e;
#pragma unroll
    for (int mk = 1; mk < 64; mk <<= 1) t += __shfl_xor(t, mk);
    pcw_g[(size_t)n * 64 + tid] = e / t;
  }
}

// ---------------- main fused kernel: per (n, s-block of 64) -------------------------------
// GEMM1 (K*CBext^T incl. KP), softmax_c, bw, w->LDS, GEMM2 (w*M1T), prot softmax, pw,
// eff_weights out, partial sum_s wt[s]*V[n,s,:]
__global__ __launch_bounds__(256, 2) void k_main(
    const float* __restrict__ Kg, const float* __restrict__ Vg,
    const u16* __restrict__ CBext, const u16* __restrict__ M1T,
    const float* __restrict__ cw_g, const float* __restrict__ pcw_g,
    const float* __restrict__ prot_logit,
    float* __restrict__ eff_out, float* __restrict__ partial) {
  __shared__ __align__(16) char smem[61440];
  u16*   As   = (u16*)smem;             // [64][40] bf16 (80B rows, 32 used)   phase 1
  u16*   Bs   = (u16*)(smem + 5120);    // [576][40] bf16                       phase 1
  u16*   Wh   = (u16*)smem;             // [64][264] bf16 (one 256-col half)    phase 2 overlay
  float* KPl  = (float*)(smem + 33792); // [64][65] fp32 (K*PC^T)               phase 2 overlay
  float* cwl  = (float*)(smem + 55552); // [512]
  float* pcwl = (float*)(smem + 57600); // [64]
  float* red0 = (float*)(smem + 57856); // [64][4]
  float* red1 = (float*)(smem + 58880); // [64][4]
  float* red2 = (float*)(smem + 59904); // [64][4]
  float* bwl  = (float*)(smem + 60928); // [64]
  float* wtl  = (float*)(smem + 61184); // [64]

  int n = blockIdx.x >> 3, sb = blockIdx.x & 7;
  int tid = threadIdx.x;
  int w = tid >> 6, l = tid & 63, l15 = l & 15, g = l >> 4;
  int s0 = sb * 64;

  for (int i = tid; i < 512; i += 256) cwl[i] = cw_g[(size_t)n * 512 + i];
  if (tid < 64) pcwl[tid] = pcw_g[(size_t)n * 64 + tid];

  const float* Kn = Kg + ((size_t)n * 512 + s0) * 512;

  f32x4 acc[4][9] = {};  // [row-stripe p][c-tile t]; wave w owns global tiles T = 9w..9w+8

  // -------- GEMM1: logits[s, c'] = sum_d K[s,d]*CBext[c',d], c' in [0,576) --------
  for (int ks = 0; ks < 16; ++ks) {
    int d0 = ks * 32;
    __syncthreads();
#pragma unroll
    for (int pp = 0; pp < 2; ++pp) {  // stage A: 64x32 fp32->bf16
      int i = pp * 256 + tid;
      int row = i >> 3, seg = i & 7;
      float4 v4 = *(const float4*)(Kn + (size_t)row * 512 + d0 + seg * 4);
      ushort4 o;
      o.x = f2bf(v4.x); o.y = f2bf(v4.y); o.z = f2bf(v4.z); o.w = f2bf(v4.w);
      *(ushort4*)(As + row * 40 + seg * 4) = o;
    }
#pragma unroll
    for (int pp = 0; pp < 9; ++pp) {  // stage B: 576x32 bf16
      int i = pp * 256 + tid;
      int row = i >> 2, seg = i & 3;
      uint4 v4 = *(const uint4*)(CBext + (size_t)row * 512 + d0 + seg * 8);
      *(uint4*)(Bs + row * 40 + seg * 8) = v4;
    }
    __syncthreads();
    bf16x8 af[4];
#pragma unroll
    for (int p = 0; p < 4; ++p)
      af[p] = *(const bf16x8*)(As + (p * 16 + l15) * 40 + g * 8);
#pragma unroll
    for (int t = 0; t < 9; ++t) {
      bf16x8 bf = *(const bf16x8*)(Bs + ((w * 9 + t) * 16 + l15) * 40 + g * 8);
#pragma unroll
      for (int p = 0; p < 4; ++p)
        acc[p][t] = __builtin_amdgcn_mfma_f32_16x16x32_bf16(af[p], bf, acc[p][t], 0, 0, 0);
    }
  }

  // tiles with c<512 participate in softmax; wave 3's t=5..8 are KP (= K*PC^T, raw)
  int nsm = (w == 3) ? 5 : 9;

#pragma unroll
  for (int t = 0; t < 9; ++t)
    if (t < nsm)
#pragma unroll
      for (int p = 0; p < 4; ++p)
#pragma unroll
        for (int j = 0; j < 4; ++j)
          acc[p][t][j] *= INV_SCALE;

  // row = p*16 + g*4 + j ; col c = T*16 + l15  (verified gfx950 C-layout)
#pragma unroll
  for (int p = 0; p < 4; ++p)
#pragma unroll
    for (int j = 0; j < 4; ++j) {
      float m = -1e30f;
#pragma unroll
      for (int t = 0; t < 9; ++t)
        if (t < nsm) m = fmaxf(m, acc[p][t][j]);
      m = red16_max(m);
      if (l15 == 0) red0[(p * 16 + g * 4 + j) * 4 + w] = m;
    }
  __syncthreads();
#pragma unroll
  for (int p = 0; p < 4; ++p)
#pragma unroll
    for (int j = 0; j < 4; ++j) {
      int row = p * 16 + g * 4 + j;
      float m = fmaxf(fmaxf(red0[row * 4 + 0], red0[row * 4 + 1]),
                      fmaxf(red0[row * 4 + 2], red0[row * 4 + 3]));
      float ssum = 0.f, sbw = 0.f;
#pragma unroll
      for (int t = 0; t < 9; ++t)
        if (t < nsm) {
          float e = __expf(acc[p][t][j] - m);
          acc[p][t][j] = e;
          ssum += e;
          sbw += e * cwl[(w * 9 + t) * 16 + l15];
        }
      ssum = red16_sum(ssum);
      sbw = red16_sum(sbw);
      if (l15 == 0) { red1[row * 4 + w] = ssum; red2[row * 4 + w] = sbw; }
    }
  if (w == 3) {  // export KP to LDS (raw, unscaled)
#pragma unroll
    for (int t = 5; t < 9; ++t)
#pragma unroll
      for (int p = 0; p < 4; ++p)
#pragma unroll
        for (int j = 0; j < 4; ++j)
          KPl[(p * 16 + g * 4 + j) * 65 + (t - 5) * 16 + l15] = acc[p][t][j];
  }
  __syncthreads();
  if (tid < 64) {
    float ss = red1[tid * 4] + red1[tid * 4 + 1] + red1[tid * 4 + 2] + red1[tid * 4 + 3];
    float bb = red2[tid * 4] + red2[tid * 4 + 1] + red2[tid * 4 + 2] + red2[tid * 4 + 3];
    bwl[tid] = bb / ss;  // base_weights[s]
  }
  float rinv[4][4];
#pragma unroll
  for (int p = 0; p < 4; ++p)
#pragma unroll
    for (int j = 0; j < 4; ++j) {
      int row = p * 16 + g * 4 + j;
      rinv[p][j] = 1.f / (red1[row * 4] + red1[row * 4 + 1] + red1[row * 4 + 2] + red1[row * 4 + 3]);
    }
#pragma unroll
  for (int t = 0; t < 9; ++t)
    if (t < nsm)
#pragma unroll
      for (int p = 0; p < 4; ++p)
#pragma unroll
        for (int j = 0; j < 4; ++j)
          acc[p][t][j] *= rinv[p][j];  // normalized slot_code_w

  // -------- GEMM2: WB[s,r] = sum_c w[s,c]*M1T[r][c], two 256-col halves --------
  f32x4 acc2[4] = {};
#pragma unroll
  for (int h = 0; h < 2; ++h) {
    __syncthreads();
#pragma unroll
    for (int t = 0; t < 9; ++t) {
      int T = w * 9 + t;
      if ((T >> 4) == h) {
        int cl_ = T * 16 + l15 - h * 256;
#pragma unroll
        for (int p = 0; p < 4; ++p)
#pragma unroll
          for (int j = 0; j < 4; ++j)
            Wh[(p * 16 + g * 4 + j) * 264 + cl_] = f2bf(acc[p][t][j]);
      }
    }
    __syncthreads();
#pragma unroll
    for (int kk = 0; kk < 8; ++kk) {
      bf16x8 a2[4];
#pragma unroll
      for (int p = 0; p < 4; ++p)
        a2[p] = *(const bf16x8*)(Wh + (p * 16 + l15) * 264 + kk * 32 + g * 8);
      // B fragment direct from global (M1T is 64KB, L2-resident)
      bf16x8 b2 = *(const bf16x8*)(M1T + (size_t)(w * 16 + l15) * 512 + h * 256 + kk * 32 + g * 8);
#pragma unroll
      for (int p = 0; p < 4; ++p)
        acc2[p] = __builtin_amdgcn_mfma_f32_16x16x32_bf16(a2[p], b2, acc2[p], 0, 0, 0);
    }
  }

  // -------- protected softmax over r (wave w owns r = 16w..16w+15) --------
  float plg[4][4];
#pragma unroll
  for (int p = 0; p < 4; ++p)
#pragma unroll
    for (int j = 0; j < 4; ++j) {
      int row = p * 16 + g * 4 + j;
      plg[p][j] = (KPl[row * 65 + w * 16 + l15] - acc2[p][j]) * INV_SCALE;
    }
#pragma unroll
  for (int p = 0; p < 4; ++p)
#pragma unroll
    for (int j = 0; j < 4; ++j) {
      float m = red16_max(plg[p][j]);
      if (l15 == 0) red0[(p * 16 + g * 4 + j) * 4 + w] = m;
    }
  __syncthreads();
#pragma unroll
  for (int p = 0; p < 4; ++p)
#pragma unroll
    for (int j = 0; j < 4; ++j) {
      int row = p * 16 + g * 4 + j;
      float m = fmaxf(fmaxf(red0[row * 4 + 0], red0[row * 4 + 1]),
                      fmaxf(red0[row * 4 + 2], red0[row * 4 + 3]));
      float e = __expf(plg[p][j] - m);
      float ssum = red16_sum(e);
      float spw = red16_sum(e * pcwl[w * 16 + l15]);
      if (l15 == 0) { red1[row * 4 + w] = ssum; red2[row * 4 + w] = spw; }
    }
  __syncthreads();
  if (tid < 64) {
    float ss = red1[tid * 4] + red1[tid * 4 + 1] + red1[tid * 4 + 2] + red1[tid * 4 + 3];
    float pw = (red2[tid * 4] + red2[tid * 4 + 1] + red2[tid * 4 + 2] + red2[tid * 4 + 3]) / ss;
    float gate = 1.f / (1.f + __expf(-prot_logit[0]));
    float wt = bwl[tid] + gate * pw;
    wtl[tid] = wt;
    eff_out[(size_t)n * 512 + s0 + tid] = wt / (1.f + gate);
  }
  __syncthreads();

  // -------- partial summary: sum over this s-block of wt[s]*V[n,s,:] --------
  const float* Vn = Vg + ((size_t)n * 512 + s0) * 512;
  float p0 = 0.f, p1 = 0.f;
#pragma unroll 4
  for (int s = 0; s < 64; ++s) {
    float wv = wtl[s];
    p0 += wv * Vn[(size_t)s * 512 + tid];
    p1 += wv * Vn[(size_t)s * 512 + tid + 256];
  }
  float* po = partial + (size_t)(n * 8 + sb) * 512;
  po[tid] = p0;
  po[tid + 256] = p1;
}

// ---------------- reduce partials -> summary[256][512] ------------------------------------
__global__ __launch_bounds__(256) void k_red(const float* __restrict__ partial,
                                             float* __restrict__ summary) {
  int idx = blockIdx.x * 256 + threadIdx.x;  // 131072
  int n = idx >> 9, d = idx & 511;
  float s = 0.f;
#pragma unroll
  for (int b = 0; b < 8; ++b) s += partial[(size_t)(n * 8 + b) * 512 + d];
  summary[idx] = s;
}

// ---------------- epilogue: logits = summary@clfW^T + b ; recon = summary@recW^T + b ------
__global__ __launch_bounds__(256) void k_out(const float* __restrict__ summary,
                                             const float* __restrict__ clfW,
                                             const float* __restrict__ clfb,
                                             const float* __restrict__ recW,
                                             const float* __restrict__ recb,
                                             float* __restrict__ out) {
  __shared__ float Sc[64][68];
  __shared__ float Wc[64][68];
  int bb = blockIdx.x;
  int is_log = (bb < 64) ? 1 : 0;
  int lb = is_log ? bb : (bb - 64);
  int kt = is_log ? (lb & 15) : (lb & 7);
  int nt = is_log ? (lb >> 4) : (lb >> 3);
  int K_rows = is_log ? 1000 : 512;
  const float* W = is_log ? clfW : recW;
  const float* bias = is_log ? clfb : recb;
  float* O = out + (is_log ? 0 : 256000);
  int no = nt * 64, ko = kt * 64;
  int tid = threadIdx.x;
  int tr = tid >> 4, tc = tid & 15;
  float acc[4][4];
#pragma unroll
  for (int i = 0; i < 4; ++i)
#pragma unroll
    for (int j = 0; j < 4; ++j) acc[i][j] = 0.f;
  for (int dc = 0; dc < 512; dc += 64) {
    __syncthreads();
#pragma unroll
    for (int pp = 0; pp < 4; ++pp) {
      int i = pp * 256 + tid;
      int row = i >> 4, seg = i & 15;
      *(float4*)&Sc[row][seg * 4] =
          *(const float4*)(summary + (size_t)(no + row) * 512 + dc + seg * 4);
      int wr = ko + row;
      float4 wv;
      if (wr < K_rows) wv = *(const float4*)(W + (size_t)wr * 512 + dc + seg * 4);
      else { wv.x = 0.f; wv.y = 0.f; wv.z = 0.f; wv.w = 0.f; }
      *(float4*)&Wc[row][seg * 4] = wv;
    }
    __syncthreads();
    for (int dd = 0; dd < 64; ++dd) {
      float av[4], bv[4];
#pragma unroll
      for (int i = 0; i < 4; ++i) av[i] = Sc[tr * 4 + i][dd];
#pragma unroll
      for (int j = 0; j < 4; ++j) bv[j] = Wc[tc * 4 + j][dd];
#pragma unroll
      for (int i = 0; i < 4; ++i)
#pragma unroll
        for (int j = 0; j < 4; ++j) acc[i][j] += av[i] * bv[j];
    }
  }
#pragma unroll
  for (int i = 0; i < 4; ++i) {
    int rn = no + tr * 4 + i;
#pragma unroll
    for (int j = 0; j < 4; ++j) {
      int k = ko + tc * 4 + j;
      if (k < K_rows) O[(size_t)rn * K_rows + k] = acc[i][j] + bias[k];
    }
  }
}

extern "C" void kernel_launch(void* const* d_in, const int* in_sizes, int n_in,
                              void* d_out, int out_size, void* d_ws, size_t ws_size,
                              hipStream_t stream) {
  const float* q    = (const float*)d_in[0];
  const float* K    = (const float*)d_in[1];
  const float* V    = (const float*)d_in[2];
  const float* CB   = (const float*)d_in[3];
  const float* PC   = (const float*)d_in[4];
  const float* Wq   = (const float*)d_in[5];
  const float* plg  = (const float*)d_in[6];
  const float* clfW = (const float*)d_in[7];
  const float* clfb = (const float*)d_in[8];
  const float* recW = (const float*)d_in[9];
  const float* recb = (const float*)d_in[10];
  float* out = (float*)d_out;
  char* ws = (char*)d_ws;

  u16*   CBext   = (u16*)(ws + 0);        // 589824 B
  u16*   M1T     = (u16*)(ws + 589824);   // 65536 B
  float* cw_g    = (float*)(ws + 655360); // 524288 B
  float* pcw_g   = (float*)(ws + 1179648);// 65536 B
  float* partial = (float*)(ws + 1245184);// 4194304 B
  float* summary = (float*)(ws + 5439488);// 524288 B  (total ~5.7 MB)

  k_prep1<<<1152, 256, 0, stream>>>(CB, PC, CBext);
  k_prep2<<<64, 256, 0, stream>>>(CB, PC, M1T);
  k_prep3<<<256, 256, 0, stream>>>(q, Wq, CBext, PC, cw_g, pcw_g);
  k_main<<<2048, 256, 0, stream>>>(K, V, CBext, M1T, cw_g, pcw_g, plg,
                                   out + 387072, partial);
  k_red<<<512, 256, 0, stream>>>(partial, summary);
  k_out<<<96, 256, 0, stream>>>(summary, clfW, clfb, recW, recb, out);
}